// Round 5
// baseline (409.951 us; speedup 1.0000x reference)
//
#include <hip/hip_runtime.h>

namespace {

constexpr int kB = 16;
constexpr int kM = 1024;
constexpr int kT = 4096;
constexpr int kD = 512;

typedef __attribute__((ext_vector_type(8))) short bfrag8;
typedef __attribute__((ext_vector_type(4))) float f4acc;

#define VM_WAIT(n) asm volatile("s_waitcnt vmcnt(" #n ")" ::: "memory")
#define LGKM0 asm volatile("s_waitcnt lgkmcnt(0)" ::: "memory")
#define SCHEDB __builtin_amdgcn_sched_barrier(0)

__device__ __forceinline__ ushort f2bf(float f) {
  unsigned u = __float_as_uint(f);
  u += 0x7fffu + ((u >> 16) & 1u);
  return (ushort)(u >> 16);
}
__device__ __forceinline__ float bf2f(ushort h) {
  return __uint_as_float(((unsigned)h) << 16);
}

__device__ __forceinline__ void gload_lds16(const void* g, void* l) {
  __builtin_amdgcn_global_load_lds(
      (const __attribute__((address_space(1))) void*)g,
      (__attribute__((address_space(3))) void*)l, 16, 0, 0);
}

// ---------------- fp32 -> bf16 conversion (weights) ----------------
__global__ __launch_bounds__(256) void cvt_bf16_k(
    const float4* __restrict__ in, ushort4* __restrict__ out, int n4)
{
  int i = blockIdx.x * 256 + threadIdx.x;
  if (i >= n4) return;
  float4 v = in[i];
  ushort4 o;
  o.x = f2bf(v.x); o.y = f2bf(v.y); o.z = f2bf(v.z); o.w = f2bf(v.w);
  out[i] = o;
}

// ---------------- Wcomb[d,k] = sum_e Wr2[e,k] * Wt[d, 512+e]  (fp32 -> bf16) ----
__global__ __launch_bounds__(512) void wcomb_k(
    const float* __restrict__ Wr2, const float* __restrict__ Wt,
    ushort* __restrict__ Wcb)
{
  __shared__ float wrow[4][512];
  int d0 = blockIdx.x * 4;  // 128 blocks
  int k = threadIdx.x;
#pragma unroll
  for (int i = 0; i < 4; ++i)
    wrow[i][k] = Wt[(size_t)(d0 + i) * 1536 + 512 + k];
  __syncthreads();
  float acc[4] = {0.f, 0.f, 0.f, 0.f};
  for (int e = 0; e < 512; ++e) {
    float wv = Wr2[e * 512 + k];
#pragma unroll
    for (int i = 0; i < 4; ++i) acc[i] = fmaf(wv, wrow[i][e], acc[i]);
  }
#pragma unroll
  for (int i = 0; i < 4; ++i) Wcb[(d0 + i) * 512 + k] = f2bf(acc[i]);
}

// ---------------- gather emb rows -> bf16 ----------------
__global__ __launch_bounds__(256) void gather_bf16_k(
    const float4* __restrict__ embv, const int* __restrict__ ids,
    ushort4* __restrict__ outv, int nrows)
{
  int i = blockIdx.x * 256 + threadIdx.x;
  if (i >= nrows * 128) return;
  int row = i >> 7;
  int c = i & 127;
  int id = ids[row];
  float4 v = embv[(size_t)id * 128 + c];
  ushort4 o;
  o.x = f2bf(v.x); o.y = f2bf(v.y); o.z = f2bf(v.z); o.w = f2bf(v.w);
  outv[i] = o;
}

// ---------------- CSR build, O(T) atomic counting-sort (deterministic) ----------
__global__ __launch_bounds__(256) void zero_k(int* __restrict__ p, int n) {
  int i = blockIdx.x * 256 + threadIdx.x;
  if (i < n) p[i] = 0;
}

__global__ __launch_bounds__(256) void deg_count_k(
    const int* __restrict__ headp, const int* __restrict__ tailp,
    const int* __restrict__ lblp, int* __restrict__ deg)
{
  int i = blockIdx.x * 256 + threadIdx.x;  // 0..B*T
  if (i >= kB * kT) return;
  if (lblp[i] == -1) return;
  int b = i >> 12;
  atomicAdd(&deg[(b << 10) + tailp[i]], 1);
  atomicAdd(&deg[(b << 10) + headp[i]], 1);
}

__global__ __launch_bounds__(1024) void scan_k(
    const int* __restrict__ deg, int* __restrict__ rowstart,
    int* __restrict__ fillptr)
{
  __shared__ int s[kM];
  int b = blockIdx.x;
  int tid = threadIdx.x;
  int d = deg[b * kM + tid];
  s[tid] = d;
  __syncthreads();
  for (int off = 1; off < kM; off <<= 1) {
    int add = (tid >= off) ? s[tid - off] : 0;
    __syncthreads();
    s[tid] += add;
    __syncthreads();
  }
  int rs = b * (2 * kT) + s[tid] - d;
  rowstart[b * kM + tid] = rs;
  fillptr[b * kM + tid] = rs;
}

// pack: (seq = 2t + isHeadEntry) << 10 | src   (seq<=8191: 13b, src<=1023: 10b)
__global__ __launch_bounds__(256) void fill_k(
    const int* __restrict__ headp, const int* __restrict__ tailp,
    const int* __restrict__ lblp, int* __restrict__ fillptr,
    int* __restrict__ epack)
{
  int i = blockIdx.x * 256 + threadIdx.x;
  if (i >= kB * kT) return;
  if (lblp[i] == -1) return;
  int b = i >> 12;
  int t = i & (kT - 1);
  int hd = headp[i];
  int tl = tailp[i];
  int p0 = atomicAdd(&fillptr[(b << 10) + tl], 1);
  epack[p0] = ((t * 2) << 10) | hd;
  int p1 = atomicAdd(&fillptr[(b << 10) + hd], 1);
  epack[p1] = ((t * 2 + 1) << 10) | tl;
}

// per-node insertion sort by packed key -> exact reference order, deterministic
__global__ __launch_bounds__(256) void sort_k(
    const int* __restrict__ rowstart, const int* __restrict__ deg,
    int* __restrict__ epack)
{
  int bm = blockIdx.x * 256 + threadIdx.x;
  if (bm >= kB * kM) return;
  int rs = rowstart[bm];
  int dg = deg[bm];
  for (int i = 1; i < dg; ++i) {
    int key = epack[rs + i];
    int j = i - 1;
    while (j >= 0 && epack[rs + j] > key) {
      epack[rs + j + 1] = epack[rs + j];
      --j;
    }
    epack[rs + j + 1] = key;
  }
}

// ---------------- U = aggregated messages / max(cnt,1), bf16 in/out ----------------
__global__ __launch_bounds__(128) void compute_upd_k(
    const ushort4* __restrict__ Xbf, const ushort4* __restrict__ Rbf,
    const int* __restrict__ deg, const int* __restrict__ rowstart,
    const int* __restrict__ epack,
    ushort4* __restrict__ Ubf)
{
  int bm = blockIdx.x;
  int b = bm >> 10;
  int tid = threadIdx.x;  // 128 threads x 4 elems = 512
  int dg = deg[bm];
  int rs = rowstart[bm];
  float ax = 0.f, ay = 0.f, az = 0.f, aw = 0.f;
  size_t xbase = (size_t)b * kM * 128;
  size_t rbase = (size_t)b * kT * 128;
  for (int e = 0; e < dg; ++e) {
    int pk = epack[rs + e];
    int src = pk & 1023;
    int rl = pk >> 11;
    ushort4 xv = Xbf[xbase + (size_t)src * 128 + tid];
    ushort4 rv = Rbf[rbase + (size_t)rl * 128 + tid];
    ax += bf2f(xv.x) - bf2f(rv.x);
    ay += bf2f(xv.y) - bf2f(rv.y);
    az += bf2f(xv.z) - bf2f(rv.z);
    aw += bf2f(xv.w) - bf2f(rv.w);
  }
  float s = 1.0f / (float)(dg > 0 ? dg : 1);
  ushort4 o;
  o.x = f2bf(ax * s); o.y = f2bf(ay * s); o.z = f2bf(az * s); o.w = f2bf(aw * s);
  Ubf[(size_t)bm * 128 + tid] = o;
}

// ---------------- deep-pipelined bf16 MFMA GEMM (256-row tiles) ----------------
// C[r, e] = sum_k A[r,k] * W[e,k]
// MODE 0: A = [Xbf | Ubf] (K=1024), W = [Ws|Wn] -> relu -> outbf.  BN=128
// MODE 1: A = Rbf (K=512), W = Wr -> outbf.                        BN=256
// MODE 2: A = [Xbf[head] | Rbf | Xbf[tail]] (K=1536),
//         W = [Wt1 s1536 | Wcomb s512 | Wt3 s1536+1024] -> outf.   BN=256
// Structure: BM=256, k-panels of 32, ring of 4 LDS slots, 512 thr (8 waves 2x4).
// Per phase: ds_read panel c -> lgkmcnt(0) -> barrier -> stage panel c+4 into
// freed slot -> setprio(1) 32 MFMA setprio(0) -> counted vmcnt -> barrier.
// Race-free: a slot is re-staged only after the barrier ending its reads; the
// stage's landing is enforced by vmcnt(3*LPP) 4 phases later.
template<int MODE>
__global__ __launch_bounds__(512, 2) void gemm256_k(
    const ushort* __restrict__ Xbf, const ushort* __restrict__ Ubf,
    const ushort* __restrict__ Rbf,
    const ushort* __restrict__ W1, const ushort* __restrict__ W2,
    const int* __restrict__ headp, const int* __restrict__ tailp,
    float* __restrict__ outf, ushort* __restrict__ outbf)
{
  constexpr int BN = (MODE == 0) ? 128 : 256;
  constexpr int NSEG = (MODE == 0) ? 2 : (MODE == 1) ? 1 : 3;
  constexpr int NP = NSEG * 16;        // k-panels of 32
  constexpr int NI = BN / 64;          // b-frags per wave: 2 or 4
  constexpr int JB = BN / 128;         // B stage instrs per wave: 1 or 2
  constexpr int LPP = 2 + JB;          // stage instrs per wave per panel
  constexpr int ASLOT = 16384;         // 256 rows x 32 k x 2B
  constexpr int BSLOT = BN * 64;       // BN rows x 32 k x 2B
  constexpr int NC = 512 / BN;         // col blocks

  __shared__ __align__(16) char lds[4 * (ASLOT + BSLOT)];
  char* Areg = lds;
  char* Breg = lds + 4 * ASLOT;

  const int tid = threadIdx.x;
  const int w = tid >> 6;
  const int l = tid & 63;
  const int wr = w >> 2;   // 0..1
  const int wc = w & 3;    // 0..3

  // XCD panel-grouping: all col-blocks of a panel on one XCD (bid%8 assumed)
  const int b = blockIdx.x;
  const int xcd = b & 7;
  const int idx = b >> 3;
  const int panel = xcd * ((int)gridDim.x >> 3) / NC + idx / NC;
  const int col = idx & (NC - 1);
  const int rowBase = panel * 256;
  const int colBase = col * BN;

  f4acc acc[8][NI];
#pragma unroll
  for (int i = 0; i < 8; ++i)
#pragma unroll
    for (int j = 0; j < NI; ++j) acc[i][j] = (f4acc)(0.f);

  // ---- per-thread staging source pointers (linear LDS dest, inverse-swz src) ----
  const ushort *aS0[2], *aS1[2], *aS2[2];
  const ushort *bS0[2], *bS1[2], *bS2[2];
#pragma unroll
  for (int j = 0; j < 2; ++j) {
    int G = w * 128 + j * 64 + l;           // A granule 0..1023
    int row = G >> 2;
    int g = (G & 3) ^ ((row >> 1) & 3);     // swizzle involution
    int grow = rowBase + row;
    if constexpr (MODE == 0) {
      aS0[j] = Xbf + (size_t)grow * kD + g * 8;
      aS1[j] = Ubf + (size_t)grow * kD + g * 8;
      aS2[j] = aS0[j];
    } else if constexpr (MODE == 1) {
      aS0[j] = Rbf + (size_t)grow * kD + g * 8;
      aS1[j] = aS0[j];
      aS2[j] = aS0[j];
    } else {
      int bb = grow >> 12;
      aS0[j] = Xbf + ((size_t)(bb << 10) + headp[grow]) * kD + g * 8;
      aS1[j] = Rbf + (size_t)grow * kD + g * 8;
      aS2[j] = Xbf + ((size_t)(bb << 10) + tailp[grow]) * kD + g * 8;
    }
  }
#pragma unroll
  for (int j = 0; j < JB; ++j) {
    int G = w * (JB * 64) + j * 64 + l;     // B granule
    int row = G >> 2;
    int g = (G & 3) ^ ((row >> 1) & 3);
    int e = colBase + row;
    if constexpr (MODE == 0) {
      bS0[j] = W1 + (size_t)e * kD + g * 8;
      bS1[j] = W2 + (size_t)e * kD + g * 8;
      bS2[j] = bS0[j];
    } else if constexpr (MODE == 1) {
      bS0[j] = W1 + (size_t)e * kD + g * 8;
      bS1[j] = bS0[j];
      bS2[j] = bS0[j];
    } else {
      bS0[j] = W1 + (size_t)e * 1536 + g * 8;
      bS1[j] = W2 + (size_t)e * 512 + g * 8;
      bS2[j] = W1 + (size_t)e * 1536 + 1024 + g * 8;
    }
  }

  auto STAGE = [&](int pan) {
    if (pan >= NP) return;
    const int seg = pan >> 4;
    const int kloc = (pan & 15) * 32;   // elements within segment
    const int slot = pan & 3;
    char* adst = Areg + slot * ASLOT + w * 2048;
#pragma unroll
    for (int j = 0; j < 2; ++j) {
      const ushort* s;
      if constexpr (NSEG == 1) s = aS0[j];
      else if constexpr (NSEG == 2) s = (seg == 0) ? aS0[j] : aS1[j];
      else s = (seg == 0) ? aS0[j] : ((seg == 1) ? aS1[j] : aS2[j]);
      gload_lds16(s + kloc, adst + j * 1024);
    }
    char* bdst = Breg + slot * BSLOT + w * (JB * 1024);
#pragma unroll
    for (int j = 0; j < JB; ++j) {
      const ushort* s;
      if constexpr (NSEG == 1) s = bS0[j];
      else if constexpr (NSEG == 2) s = (seg == 0) ? bS0[j] : bS1[j];
      else s = (seg == 0) ? bS0[j] : ((seg == 1) ? bS1[j] : bS2[j]);
      gload_lds16(s + kloc, bdst + j * 1024);
    }
  };

  // ---- prologue: stage panels 0..3, wait panel 0 ----
#pragma unroll
  for (int p = 0; p < 4; ++p) STAGE(p);
  if constexpr (LPP == 4) VM_WAIT(12); else VM_WAIT(9);
  SCHEDB;
  __builtin_amdgcn_s_barrier();
  SCHEDB;

  const int arowb = wr * 128 + (l & 15);
  const int erowb = wc * (BN / 4) + (l & 15);
  const int gq = l >> 4;

  for (int c = 0; c < NP; ++c) {
    const char* Ab = Areg + (c & 3) * ASLOT;
    const char* Bb = Breg + (c & 3) * BSLOT;
    bfrag8 af[8], bf[NI];
#pragma unroll
    for (int mi = 0; mi < 8; ++mi) {
      int row = arowb + mi * 16;
      af[mi] = *(const bfrag8*)(Ab + row * 64 + (gq ^ ((row >> 1) & 3)) * 16);
    }
#pragma unroll
    for (int ni = 0; ni < NI; ++ni) {
      int e = erowb + ni * 16;
      bf[ni] = *(const bfrag8*)(Bb + e * 64 + (gq ^ ((e >> 1) & 3)) * 16);
    }
    LGKM0;        // all reads of panel c retired (race safety)
    SCHEDB;
    __builtin_amdgcn_s_barrier();
    SCHEDB;
    STAGE(c + 4); // into slot (c&3), just freed
    __builtin_amdgcn_s_setprio(1);
#pragma unroll
    for (int mi = 0; mi < 8; ++mi)
#pragma unroll
      for (int ni = 0; ni < NI; ++ni)
        acc[mi][ni] = __builtin_amdgcn_mfma_f32_16x16x32_bf16(
            af[mi], bf[ni], acc[mi][ni], 0, 0, 0);
    __builtin_amdgcn_s_setprio(0);
    SCHEDB;
    if (c < NP - 1) {  // counted wait: panel c+1 landed, <=3 panels in flight
      int m2 = NP - 2 - c;
      if constexpr (LPP == 4) {
        if (m2 >= 3) VM_WAIT(12);
        else if (m2 == 2) VM_WAIT(8);
        else if (m2 == 1) VM_WAIT(4);
        else VM_WAIT(0);
      } else {
        if (m2 >= 3) VM_WAIT(9);
        else if (m2 == 2) VM_WAIT(6);
        else if (m2 == 1) VM_WAIT(3);
        else VM_WAIT(0);
      }
    }
    SCHEDB;
    __builtin_amdgcn_s_barrier();
    SCHEDB;
  }

  // ---- epilogue: C/D layout col = lane&15, row = (lane>>4)*4 + q ----
#pragma unroll
  for (int mi = 0; mi < 8; ++mi) {
#pragma unroll
    for (int ni = 0; ni < NI; ++ni) {
#pragma unroll
      for (int q = 0; q < 4; ++q) {
        int rr = rowBase + wr * 128 + mi * 16 + (l >> 4) * 4 + q;
        int cc = colBase + wc * (BN / 4) + ni * 16 + (l & 15);
        float v = acc[mi][ni][q];
        if constexpr (MODE == 0) v = fmaxf(v, 0.f);
        if constexpr (MODE == 2) outf[(size_t)rr * kD + cc] = v;
        else outbf[(size_t)rr * kD + cc] = f2bf(v);
      }
    }
  }
}

// ---------------- encoded_cause reduction (2-pass, deterministic) ----------------
__global__ __launch_bounds__(128) void reduce1_k(
    const float4* __restrict__ outv, float4* __restrict__ part)
{
  int blk = blockIdx.x;
  int b = blk >> 4;
  int c = blk & 15;
  int tid = threadIdx.x;
  float ax = 0.f, ay = 0.f, az = 0.f, aw = 0.f;
  size_t base = ((size_t)b * kT + (size_t)c * 256) * 128;
  for (int t = 0; t < 256; ++t) {
    float4 v = outv[base + (size_t)t * 128 + tid];
    ax += v.x; ay += v.y; az += v.z; aw += v.w;
  }
  float4 o; o.x = ax; o.y = ay; o.z = az; o.w = aw;
  part[(size_t)blk * 128 + tid] = o;
}

__global__ __launch_bounds__(128) void reduce2_k(
    const float4* __restrict__ part, float4* __restrict__ enc)
{
  int b = blockIdx.x;
  int tid = threadIdx.x;
  float ax = 0.f, ay = 0.f, az = 0.f, aw = 0.f;
  for (int c = 0; c < 16; ++c) {
    float4 v = part[((size_t)(b * 16 + c)) * 128 + tid];
    ax += v.x; ay += v.y; az += v.z; aw += v.w;
  }
  float4 o; o.x = ax; o.y = ay; o.z = az; o.w = aw;
  enc[(size_t)b * 128 + tid] = o;
}

}  // namespace

extern "C" void kernel_launch(void* const* d_in, const int* in_sizes, int n_in,
                              void* d_out, int out_size, void* d_ws, size_t ws_size,
                              hipStream_t stream) {
  const float* emb = (const float*)d_in[0];
  const float* Ws = (const float*)d_in[1];
  const float* Wn = (const float*)d_in[2];
  const float* Wr = (const float*)d_in[3];
  const float* Wt = (const float*)d_in[4];
  const int* cid = (const int*)d_in[5];
  const int* relid = (const int*)d_in[6];
  const int* headp = (const int*)d_in[7];
  const int* tailp = (const int*)d_in[8];
  const int* lblp = (const int*)d_in[9];
  float* out = (float*)d_out;

  // ---- workspace layout (bytes), <= 88 MB ----
  char* wsp = (char*)d_ws;
  ushort* Xa  = (ushort*)(wsp);                         // 16 MB (X ping)
  ushort* R1  = (ushort*)(wsp + (16ull << 20));         // 64 MB (rel after hop 1)
  ushort* Wsb = (ushort*)(wsp + (80ull << 20));         // 1 MB (2 hops)
  ushort* Wnb = (ushort*)(wsp + (81ull << 20));         // 1 MB
  ushort* Wrb = (ushort*)(wsp + (82ull << 20));         // 0.5 MB (hop 1 only)
  ushort* Wcb = (ushort*)(wsp + (82ull << 20) + (512ull << 10));  // 0.5 MB Wcomb
  ushort* Wtb = (ushort*)(wsp + (83ull << 20));         // 1.5 MB
  int* deg      = (int*)(wsp + (85ull << 20));          // 64 KB
  int* rowstart = deg + kB * kM;                        // 64 KB
  int* fillptr  = rowstart + kB * kM;                   // 64 KB
  int* epack    = fillptr + kB * kM;                    // 512 KB
  float* part   = (float*)(wsp + (87ull << 20));        // 0.5 MB

  // ---- d_out region doubles as hop-intermediate scratch (dead before MODE2) ----
  char* outc = (char*)d_out;
  ushort* R0 = (ushort*)(outc);                  // 64 MB (gathered rel)
  ushort* Xb = (ushort*)(outc + (64ull << 20));  // 16 MB (X pong)
  ushort* Ub = (ushort*)(outc + (80ull << 20));  // 16 MB (ends at 96 MB < 128 MB)
  float* ENC = out + (size_t)kB * kT * kD;

  // weights -> bf16 (+ Wcomb fold of hop-2 Wr into Wt middle segment)
  cvt_bf16_k<<<512, 256, 0, stream>>>((const float4*)Ws, (ushort4*)Wsb, 2 * kD * kD / 4);
  cvt_bf16_k<<<512, 256, 0, stream>>>((const float4*)Wn, (ushort4*)Wnb, 2 * kD * kD / 4);
  cvt_bf16_k<<<256, 256, 0, stream>>>((const float4*)Wr, (ushort4*)Wrb, kD * kD / 4);
  cvt_bf16_k<<<768, 256, 0, stream>>>((const float4*)Wt, (ushort4*)Wtb, kD * 1536 / 4);
  wcomb_k<<<128, 512, 0, stream>>>(Wr + (size_t)kD * kD, Wt, Wcb);

  // gather embeddings -> bf16
  gather_bf16_k<<<(kB * kM * 128) / 256, 256, 0, stream>>>(
      (const float4*)emb, cid, (ushort4*)Xa, kB * kM);
  gather_bf16_k<<<(kB * kT * 128) / 256, 256, 0, stream>>>(
      (const float4*)emb, relid, (ushort4*)R0, kB * kT);

  // CSR build: zero -> count -> scan -> fill -> per-node sort (deterministic)
  zero_k<<<(kB * kM + 255) / 256, 256, 0, stream>>>(deg, kB * kM);
  deg_count_k<<<(kB * kT + 255) / 256, 256, 0, stream>>>(headp, tailp, lblp, deg);
  scan_k<<<kB, 1024, 0, stream>>>(deg, rowstart, fillptr);
  fill_k<<<(kB * kT + 255) / 256, 256, 0, stream>>>(headp, tailp, lblp, fillptr, epack);
  sort_k<<<(kB * kM + 255) / 256, 256, 0, stream>>>(rowstart, deg, epack);

  // ---- hop 1: X0(Xa) -> X1(Xb), rel0(R0) -> rel1(R1) ----
  compute_upd_k<<<kB * kM, 128, 0, stream>>>(
      (const ushort4*)Xa, (const ushort4*)R0, deg, rowstart, epack, (ushort4*)Ub);
  gemm256_k<0><<<(kB * kM / 256) * 4, 512, 0, stream>>>(
      Xa, Ub, nullptr, Wsb, Wnb, nullptr, nullptr, nullptr, Xb);
  gemm256_k<1><<<(kB * kT / 256) * 2, 512, 0, stream>>>(
      nullptr, nullptr, R0, Wrb, nullptr, nullptr, nullptr, nullptr, R1);

  // ---- hop 2: X1(Xb) -> X2(Xa); rel2 GEMM folded into Wcomb ----
  compute_upd_k<<<kB * kM, 128, 0, stream>>>(
      (const ushort4*)Xb, (const ushort4*)R1, deg, rowstart, epack, (ushort4*)Ub);
  gemm256_k<0><<<(kB * kM / 256) * 4, 512, 0, stream>>>(
      Xb, Ub, nullptr, Wsb + (size_t)kD * kD, Wnb + (size_t)kD * kD,
      nullptr, nullptr, nullptr, Xa);

  // ---- final triple GEMM: out = X2[head]@Wt1^T + rel1@Wcomb^T + X2[tail]@Wt3^T ----
  gemm256_k<2><<<(kB * kT / 256) * 2, 512, 0, stream>>>(
      Xa, nullptr, R1, Wtb, Wcb, headp, tailp, out, nullptr);

  // encoded_cause = sum over T
  reduce1_k<<<kB * 16, 128, 0, stream>>>((const float4*)out, (float4*)part);
  reduce2_k<<<kB, 128, 0, stream>>>((const float4*)part, (float4*)ENC);
}

// Round 6
// 354.706 us; speedup vs baseline: 1.1557x; 1.1557x over previous
//
#include <hip/hip_runtime.h>

namespace {

constexpr int kB = 16;
constexpr int kM = 1024;
constexpr int kT = 4096;
constexpr int kD = 512;
constexpr int kV = 32000;

typedef __attribute__((ext_vector_type(8))) short bfrag8;
typedef __attribute__((ext_vector_type(4))) float f4acc;

__device__ __forceinline__ ushort f2bf(float f) {
  unsigned u = __float_as_uint(f);
  u += 0x7fffu + ((u >> 16) & 1u);
  return (ushort)(u >> 16);
}
__device__ __forceinline__ float bf2f(ushort h) {
  return __uint_as_float(((unsigned)h) << 16);
}

__device__ __forceinline__ void gload_lds16(const void* g, void* l) {
  __builtin_amdgcn_global_load_lds(
      (const __attribute__((address_space(1))) void*)g,
      (__attribute__((address_space(3))) void*)l, 16, 0, 0);
}

// ---------------- fp32 -> bf16 conversion ----------------
__global__ __launch_bounds__(256) void cvt_bf16_k(
    const float4* __restrict__ in, ushort4* __restrict__ out, int n4)
{
  int i = blockIdx.x * 256 + threadIdx.x;
  if (i >= n4) return;
  float4 v = in[i];
  ushort4 o;
  o.x = f2bf(v.x); o.y = f2bf(v.y); o.z = f2bf(v.z); o.w = f2bf(v.w);
  out[i] = o;
}

// ---------------- small 512x512 fp32 matmul: C[e,k] = sum_a P[e,a]*Q[a,k] ----
// P row-major with stride strideP, column offset offsP. Q row-major 512.
template<int BF16OUT>
__global__ __launch_bounds__(512) void smallmm_k(
    const float* __restrict__ P, int strideP, int offsP,
    const float* __restrict__ Q,
    float* __restrict__ outf, ushort* __restrict__ outb)
{
  __shared__ float prow[4][512];
  int e0 = blockIdx.x * 4;
  int k = threadIdx.x;
#pragma unroll
  for (int i = 0; i < 4; ++i)
    prow[i][k] = P[(size_t)(e0 + i) * strideP + offsP + k];
  __syncthreads();
  float acc[4] = {0.f, 0.f, 0.f, 0.f};
  for (int a = 0; a < 512; ++a) {
    float qv = Q[a * 512 + k];
#pragma unroll
    for (int i = 0; i < 4; ++i) acc[i] = fmaf(prow[i][a], qv, acc[i]);
  }
#pragma unroll
  for (int i = 0; i < 4; ++i) {
    if constexpr (BF16OUT) outb[(e0 + i) * 512 + k] = f2bf(acc[i]);
    else outf[(e0 + i) * 512 + k] = acc[i];
  }
}

// ---------------- gather bf16 rows (1 KB each) ----------------
__global__ __launch_bounds__(256) void gather_rows16_k(
    const uint4* __restrict__ src, const int* __restrict__ ids,
    uint4* __restrict__ dst, int nrows)
{
  int i = blockIdx.x * 256 + threadIdx.x;
  if (i >= nrows * 64) return;  // 512 bf16 = 64 x 16B
  int row = i >> 6;
  int c = i & 63;
  dst[i] = src[(size_t)ids[row] * 64 + c];
}

// ---------------- CSR build, O(T) atomic counting-sort (deterministic) ----------
__global__ __launch_bounds__(256) void zero_k(int* __restrict__ p, int n) {
  int i = blockIdx.x * 256 + threadIdx.x;
  if (i < n) p[i] = 0;
}

__global__ __launch_bounds__(256) void deg_count_k(
    const int* __restrict__ headp, const int* __restrict__ tailp,
    const int* __restrict__ lblp, int* __restrict__ deg)
{
  int i = blockIdx.x * 256 + threadIdx.x;
  if (i >= kB * kT) return;
  if (lblp[i] == -1) return;
  int b = i >> 12;
  atomicAdd(&deg[(b << 10) + tailp[i]], 1);
  atomicAdd(&deg[(b << 10) + headp[i]], 1);
}

__global__ __launch_bounds__(1024) void scan_k(
    const int* __restrict__ deg, int* __restrict__ rowstart,
    int* __restrict__ fillptr)
{
  __shared__ int s[kM];
  int b = blockIdx.x;
  int tid = threadIdx.x;
  int d = deg[b * kM + tid];
  s[tid] = d;
  __syncthreads();
  for (int off = 1; off < kM; off <<= 1) {
    int add = (tid >= off) ? s[tid - off] : 0;
    __syncthreads();
    s[tid] += add;
    __syncthreads();
  }
  int rs = b * (2 * kT) + s[tid] - d;
  rowstart[b * kM + tid] = rs;
  fillptr[b * kM + tid] = rs;
}

// pack: (seq = 2t + isHeadEntry) << 10 | src
__global__ __launch_bounds__(256) void fill_k(
    const int* __restrict__ headp, const int* __restrict__ tailp,
    const int* __restrict__ lblp, int* __restrict__ fillptr,
    int* __restrict__ epack)
{
  int i = blockIdx.x * 256 + threadIdx.x;
  if (i >= kB * kT) return;
  if (lblp[i] == -1) return;
  int b = i >> 12;
  int t = i & (kT - 1);
  int hd = headp[i];
  int tl = tailp[i];
  int p0 = atomicAdd(&fillptr[(b << 10) + tl], 1);
  epack[p0] = ((t * 2) << 10) | hd;
  int p1 = atomicAdd(&fillptr[(b << 10) + hd], 1);
  epack[p1] = ((t * 2 + 1) << 10) | tl;
}

__global__ __launch_bounds__(256) void sort_k(
    const int* __restrict__ rowstart, const int* __restrict__ deg,
    int* __restrict__ epack)
{
  int bm = blockIdx.x * 256 + threadIdx.x;
  if (bm >= kB * kM) return;
  int rs = rowstart[bm];
  int dg = deg[bm];
  for (int i = 1; i < dg; ++i) {
    int key = epack[rs + i];
    int j = i - 1;
    while (j >= 0 && epack[rs + j] > key) {
      epack[rs + j + 1] = epack[rs + j];
      --j;
    }
    epack[rs + j + 1] = key;
  }
}

// ---------------- nSr0n[bm] = -(sum_edges EMBb[relid[t]]) / max(cnt,1) ----------
__global__ __launch_bounds__(128) void agg_rel_k(
    const ushort4* __restrict__ EMBv, const int* __restrict__ relid,
    const int* __restrict__ deg, const int* __restrict__ rowstart,
    const int* __restrict__ epack, ushort4* __restrict__ outv)
{
  int bm = blockIdx.x;
  int b = bm >> 10;
  int tid = threadIdx.x;
  int dg = deg[bm];
  int rs = rowstart[bm];
  const int* rid = relid + (b << 12);
  float ax = 0.f, ay = 0.f, az = 0.f, aw = 0.f;
  for (int e = 0; e < dg; ++e) {
    int t = epack[rs + e] >> 11;
    int id = rid[t];
    ushort4 rv = EMBv[(size_t)id * 128 + tid];
    ax += bf2f(rv.x); ay += bf2f(rv.y); az += bf2f(rv.z); aw += bf2f(rv.w);
  }
  float s = -1.0f / (float)(dg > 0 ? dg : 1);
  ushort4 o;
  o.x = f2bf(ax * s); o.y = f2bf(ay * s); o.z = f2bf(az * s); o.w = f2bf(aw * s);
  outv[(size_t)bm * 128 + tid] = o;
}

// ---------------- Sxn[bm] = (sum_edges X[src]) / max(cnt,1) ----------
__global__ __launch_bounds__(128) void agg_x_k(
    const ushort4* __restrict__ Xv,
    const int* __restrict__ deg, const int* __restrict__ rowstart,
    const int* __restrict__ epack, ushort4* __restrict__ outv)
{
  int bm = blockIdx.x;
  int b = bm >> 10;
  int tid = threadIdx.x;
  int dg = deg[bm];
  int rs = rowstart[bm];
  size_t xbase = (size_t)b * kM * 128;
  float ax = 0.f, ay = 0.f, az = 0.f, aw = 0.f;
  for (int e = 0; e < dg; ++e) {
    int src = epack[rs + e] & 1023;
    ushort4 xv = Xv[xbase + (size_t)src * 128 + tid];
    ax += bf2f(xv.x); ay += bf2f(xv.y); az += bf2f(xv.z); aw += bf2f(xv.w);
  }
  float s = 1.0f / (float)(dg > 0 ? dg : 1);
  ushort4 o;
  o.x = f2bf(ax * s); o.y = f2bf(ay * s); o.z = f2bf(az * s); o.w = f2bf(aw * s);
  outv[(size_t)bm * 128 + tid] = o;
}

// ---------------- bf16 MFMA GEMM (128x128 tile, proven m97 structure) --------
// MODE 0: C = relu([X|Sxn|nSr0n] @ [W1|W2|W3]^T), K=1536, in-place X. NC=4, SWZ.
// MODE 4: C = X2 @ [Wt1|Wt3]^T  (N=1024, HT table, bf16 out stride 1024). NC=8, SWZ.
// MODE 3: C = EMBb[relid] @ Wfold^T + HT[head].H + HT[tail].T -> fp32 out
//         + per-block column partials for encoded_cause. NC=4, no SWZ.
template<int MODE>
__global__ __launch_bounds__(256) void gemm_k(
    const ushort* __restrict__ A0, const ushort* __restrict__ A1,
    const ushort* __restrict__ A2,
    const ushort* __restrict__ W1, const ushort* __restrict__ W2,
    const ushort* __restrict__ W3,
    const int* __restrict__ relid,
    const int* __restrict__ headp, const int* __restrict__ tailp,
    const ushort* __restrict__ HT,
    float* __restrict__ outf, ushort* __restrict__ outbf,
    float* __restrict__ part)
{
  constexpr int NSEG = (MODE == 0) ? 3 : 1;
  constexpr int NC = (MODE == 4) ? 8 : 4;
  constexpr int OSTR = (MODE == 4) ? 1024 : 512;
  constexpr bool SWZ = (MODE != 3);

  __shared__ __align__(16) char lds[32768];
  char* ldsA = lds;
  char* ldsB = lds + 16384;
  const int tid = threadIdx.x;
  const int w = tid >> 6;
  const int l = tid & 63;
  const int wr = w >> 1;
  const int wc = w & 1;
  const int bid = blockIdx.x;
  int panel, col;
  if constexpr (SWZ) {
    int xcd = bid & 7;
    int idx = bid >> 3;
    panel = xcd * (((int)gridDim.x >> 3) / NC) + idx / NC;
    col = idx % NC;
  } else {
    panel = bid >> 2;
    col = bid & 3;
  }
  const int rowBase = panel * 128;
  const int colBase = col * 128;

  f4acc acc[4][4];
#pragma unroll
  for (int i = 0; i < 4; ++i)
#pragma unroll
    for (int j = 0; j < 4; ++j) acc[i][j] = (f4acc)(0.f);

  // staging geometry: granule P = (i*4+w)*64 + l, row = P>>3,
  // swizzled source column granule gc = (P&7) ^ (row&7)
  int lrow[4], gc[4];
#pragma unroll
  for (int i = 0; i < 4; ++i) {
    int P = (i * 4 + w) * 64 + l;
    lrow[i] = P >> 3;
    gc[i] = (P & 7) ^ (lrow[i] & 7);
  }

  for (int seg = 0; seg < NSEG; ++seg) {
    const char* aP[4];
    const char* bP[4];
#pragma unroll
    for (int i = 0; i < 4; ++i) {
      int grow = rowBase + lrow[i];
      const ushort* ab;
      if constexpr (MODE == 0) {
        ab = (seg == 0 ? A0 : (seg == 1 ? A1 : A2)) + (size_t)grow * kD;
      } else if constexpr (MODE == 4) {
        ab = A0 + (size_t)grow * kD;
      } else {
        ab = A0 + (size_t)relid[grow] * kD;  // gather emb row
      }
      aP[i] = (const char*)ab + gc[i] * 16;
      int e = colBase + lrow[i];
      const ushort* wb;
      if constexpr (MODE == 0) {
        wb = (seg == 0 ? W1 : (seg == 1 ? W2 : W3)) + (size_t)e * kD;
      } else if constexpr (MODE == 4) {
        wb = W1 + (size_t)(e & 511) * 1536 + (e >> 9) * 1024;
      } else {
        wb = W1 + (size_t)e * kD;
      }
      bP[i] = (const char*)wb + gc[i] * 16;
    }

    for (int kcl = 0; kcl < 8; ++kcl) {
      __syncthreads();
#pragma unroll
      for (int i = 0; i < 4; ++i) {
        gload_lds16(aP[i] + kcl * 128, ldsA + (i * 4 + w) * 1024);
        gload_lds16(bP[i] + kcl * 128, ldsB + (i * 4 + w) * 1024);
      }
      __syncthreads();
#pragma unroll
      for (int ksub = 0; ksub < 2; ++ksub) {
        bfrag8 af[4], bfv[4];
#pragma unroll
        for (int mi = 0; mi < 4; ++mi) {
          int r = wr * 64 + mi * 16 + (l & 15);
          int g = (ksub * 4 + (l >> 4)) ^ (r & 7);
          af[mi] = *(const bfrag8*)(ldsA + r * 128 + g * 16);
        }
#pragma unroll
        for (int ni = 0; ni < 4; ++ni) {
          int e = wc * 64 + ni * 16 + (l & 15);
          int g = (ksub * 4 + (l >> 4)) ^ (e & 7);
          bfv[ni] = *(const bfrag8*)(ldsB + e * 128 + g * 16);
        }
#pragma unroll
        for (int mi = 0; mi < 4; ++mi)
#pragma unroll
          for (int ni = 0; ni < 4; ++ni)
            acc[mi][ni] = __builtin_amdgcn_mfma_f32_16x16x32_bf16(
                af[mi], bfv[ni], acc[mi][ni], 0, 0, 0);
      }
    }
  }

  // ---- epilogue: C/D layout col = lane&15, row = (lane>>4)*4 + q ----
  if constexpr (MODE != 3) {
#pragma unroll
    for (int mi = 0; mi < 4; ++mi) {
#pragma unroll
      for (int ni = 0; ni < 4; ++ni) {
#pragma unroll
        for (int q = 0; q < 4; ++q) {
          int rr = rowBase + wr * 64 + mi * 16 + (l >> 4) * 4 + q;
          int cc = colBase + wc * 64 + ni * 16 + (l & 15);
          float v = acc[mi][ni][q];
          if constexpr (MODE == 0) v = fmaxf(v, 0.f);
          outbf[(size_t)rr * OSTR + cc] = f2bf(v);
        }
      }
    }
  } else {
    __shared__ float colsum[2][128];
    colsum[tid >> 7][tid & 127] = 0.f;
    __syncthreads();
    float cs[4] = {0.f, 0.f, 0.f, 0.f};
#pragma unroll
    for (int mi = 0; mi < 4; ++mi) {
#pragma unroll
      for (int q = 0; q < 4; ++q) {
        int rr = rowBase + wr * 64 + mi * 16 + (l >> 4) * 4 + q;
        int hid = headp[rr];
        int tl = tailp[rr];
        int bb = rr >> 12;
        const ushort* Hrow = HT + ((size_t)(bb << 10) + hid) * 1024;
        const ushort* Trow = HT + ((size_t)(bb << 10) + tl) * 1024 + 512;
#pragma unroll
        for (int ni = 0; ni < 4; ++ni) {
          int cc = colBase + wc * 64 + ni * 16 + (l & 15);
          float v = acc[mi][ni][q] + bf2f(Hrow[cc]) + bf2f(Trow[cc]);
          outf[(size_t)rr * 512 + cc] = v;
          cs[ni] += v;
        }
      }
    }
#pragma unroll
    for (int ni = 0; ni < 4; ++ni) {
      float s = cs[ni];
      s += __shfl_xor(s, 16, 64);
      s += __shfl_xor(s, 32, 64);
      if ((l & 48) == 0)
        colsum[wr][wc * 64 + ni * 16 + (l & 15)] = s;
    }
    __syncthreads();
    if (tid < 128) {
      int bb = rowBase >> 12;
      int rt = (rowBase >> 7) & 31;
      part[(size_t)(bb * 32 + rt) * 512 + colBase + tid] =
          colsum[0][tid] + colsum[1][tid];
    }
  }
}

// ---------------- encoded_cause: sum 32 row-tile partials per batch ----------
__global__ __launch_bounds__(512) void reduce_enc_k(
    const float* __restrict__ part, float* __restrict__ enc)
{
  int b = blockIdx.x;
  int c = threadIdx.x;
  float s = 0.f;
  for (int rt = 0; rt < 32; ++rt) s += part[(size_t)(b * 32 + rt) * 512 + c];
  enc[b * 512 + c] = s;
}

}  // namespace

extern "C" void kernel_launch(void* const* d_in, const int* in_sizes, int n_in,
                              void* d_out, int out_size, void* d_ws, size_t ws_size,
                              hipStream_t stream) {
  const float* emb = (const float*)d_in[0];
  const float* Ws = (const float*)d_in[1];
  const float* Wn = (const float*)d_in[2];
  const float* Wr = (const float*)d_in[3];
  const float* Wt = (const float*)d_in[4];
  const int* cid = (const int*)d_in[5];
  const int* relid = (const int*)d_in[6];
  const int* headp = (const int*)d_in[7];
  const int* tailp = (const int*)d_in[8];
  const int* lblp = (const int*)d_in[9];
  float* out = (float*)d_out;

  // ---- ws layout (~72 MB, well under proven 88) ----
  char* wsp = (char*)d_ws;
  ushort* EMBb  = (ushort*)(wsp);                        // 31.25 MB @0
  ushort* HT    = (ushort*)(wsp + (32ull << 20));        // 32 MB @32 (alive thru MODE3)
  ushort* Wsb   = (ushort*)(wsp + (64ull << 20));        // 1 MB (2 hops)
  ushort* Wnb   = (ushort*)(wsp + (65ull << 20));        // 1 MB (2 hops)
  ushort* Wtb   = (ushort*)(wsp + (66ull << 20));        // 1.5 MB
  ushort* Wn2r  = (ushort*)(wsp + (67ull << 20) + (512ull << 10));  // 0.5 MB
  ushort* Wfold = (ushort*)(wsp + (68ull << 20));        // 0.5 MB
  float*  T1    = (float*)(wsp + (68ull << 20) + (512ull << 10));   // 1 MB fp32
  int* deg      = (int*)(wsp + (70ull << 20));           // 64 KB
  int* rowstart = deg + kB * kM;
  int* fillptr  = rowstart + kB * kM;
  int* epack    = fillptr + kB * kM;                     // 512 KB
  float* part   = (float*)(wsp + (71ull << 20));         // 1 MB

  // ---- d_out doubles as scratch; all dead before MODE3's out write ----
  char* outc = (char*)d_out;
  ushort* X      = (ushort*)(outc);                   // 16 MB (in-place thru hops)
  ushort* Sxn    = (ushort*)(outc + (16ull << 20));   // 16 MB
  ushort* nSr0n  = (ushort*)(outc + (32ull << 20));   // 16 MB
  float* ENC = out + (size_t)kB * kT * kD;

  // emb + weights -> bf16
  cvt_bf16_k<<<(kV * kD / 4 + 255) / 256, 256, 0, stream>>>(
      (const float4*)emb, (ushort4*)EMBb, kV * kD / 4);
  cvt_bf16_k<<<512, 256, 0, stream>>>((const float4*)Ws, (ushort4*)Wsb, 2 * kD * kD / 4);
  cvt_bf16_k<<<512, 256, 0, stream>>>((const float4*)Wn, (ushort4*)Wnb, 2 * kD * kD / 4);
  cvt_bf16_k<<<768, 256, 0, stream>>>((const float4*)Wt, (ushort4*)Wtb, kD * 1536 / 4);

  // weight folds (fp32 inputs, one bf16 rounding at the end):
  // Wn2r = Wn2 . Wr1 ; Wfold = Wt2 . Wr2 . Wr1
  smallmm_k<1><<<128, 512, 0, stream>>>(Wn + (size_t)kD * kD, 512, 0, Wr, nullptr, Wn2r);
  smallmm_k<0><<<128, 512, 0, stream>>>(Wt, 1536, 512, Wr + (size_t)kD * kD, T1, nullptr);
  smallmm_k<1><<<128, 512, 0, stream>>>(T1, 512, 0, Wr, nullptr, Wfold);

  // X0 = EMBb[cid]
  gather_rows16_k<<<(kB * kM * 64) / 256, 256, 0, stream>>>(
      (const uint4*)EMBb, cid, (uint4*)X, kB * kM);

  // CSR build (deterministic)
  zero_k<<<(kB * kM + 255) / 256, 256, 0, stream>>>(deg, kB * kM);
  deg_count_k<<<(kB * kT + 255) / 256, 256, 0, stream>>>(headp, tailp, lblp, deg);
  scan_k<<<kB, 1024, 0, stream>>>(deg, rowstart, fillptr);
  fill_k<<<(kB * kT + 255) / 256, 256, 0, stream>>>(headp, tailp, lblp, fillptr, epack);
  sort_k<<<(kB * kM + 255) / 256, 256, 0, stream>>>(rowstart, deg, epack);

  // hop-invariant rel aggregate: nSr0n = -(sum EMBb[relid[t]])/cnt
  agg_rel_k<<<kB * kM, 128, 0, stream>>>(
      (const ushort4*)EMBb, relid, deg, rowstart, epack, (ushort4*)nSr0n);

  // ---- hop 1: X1 = relu(X0.Ws1^T + Sxn.Wn1^T + nSr0n.Wn1^T), in place ----
  agg_x_k<<<kB * kM, 128, 0, stream>>>(
      (const ushort4*)X, deg, rowstart, epack, (ushort4*)Sxn);
  gemm_k<0><<<(kB * kM / 128) * 4, 256, 0, stream>>>(
      X, Sxn, nSr0n, Wsb, Wnb, Wnb, nullptr, nullptr, nullptr, nullptr,
      nullptr, X, nullptr);

  // ---- hop 2: rel-hop folded via Wn2r = Wn2.Wr1 ----
  agg_x_k<<<kB * kM, 128, 0, stream>>>(
      (const ushort4*)X, deg, rowstart, epack, (ushort4*)Sxn);
  gemm_k<0><<<(kB * kM / 128) * 4, 256, 0, stream>>>(
      X, Sxn, nSr0n, Wsb + (size_t)kD * kD, Wnb + (size_t)kD * kD, Wn2r,
      nullptr, nullptr, nullptr, nullptr, nullptr, X, nullptr);

  // ---- HT = X2 @ [Wt1 | Wt3]^T  (bf16, row stride 1024) ----
  gemm_k<4><<<(kB * kM / 128) * 8, 256, 0, stream>>>(
      X, nullptr, nullptr, Wtb, nullptr, nullptr, nullptr, nullptr, nullptr,
      nullptr, nullptr, HT, nullptr);

  // ---- final: out = EMBb[relid] @ Wfold^T + H[head] + T[tail], + partials ----
  gemm_k<3><<<(kB * kT / 128) * 4, 256, 0, stream>>>(
      EMBb, nullptr, nullptr, Wfold, nullptr, nullptr, relid, headp, tailp,
      HT, out, nullptr, part);

  // encoded_cause
  reduce_enc_k<<<kB, 512, 0, stream>>>(part, ENC);
}